// Round 14
// baseline (148.816 us; speedup 1.0000x reference)
//
#include <hip/hip_runtime.h>
#include <cstddef>
#include <cstdint>

// B=8192, T=512, I=4, H=32, O=4 — 2-layer tanh RNN + linear head, fp32 I/O.
constexpr int kB = 8192, kT = 512, kI = 4, kH = 32, kO = 4;

typedef _Float16 f16x8 __attribute__((ext_vector_type(8)));
typedef float    f32x4 __attribute__((ext_vector_type(4)));

#define MFMA(a, b, c) __builtin_amdgcn_mfma_f32_16x16x32_f16((a), (b), (c), 0, 0, 0)

// Barrier waiting on LDS ops only (global loads/stores stay in flight).
__device__ __forceinline__ void bar_lds() {
    asm volatile("s_waitcnt lgkmcnt(0)" ::: "memory");
    __builtin_amdgcn_s_barrier();
    __builtin_amdgcn_sched_barrier(0);
}

__device__ __forceinline__ float fast_tanh(float x) {
    // tanh(x) = 1 - 2/(e^{2x}+1); exp2-based, saturates correctly, rel err ~1e-6
    float e = __builtin_amdgcn_exp2f(x * 2.8853900817779268f);
    return 1.0f - 2.0f * __builtin_amdgcn_rcpf(e + 1.0f);
}

__device__ __forceinline__ float4 ld4(const float* p) { return *(const float4*)p; }

// A/B fragment from two float4s: elems 0-3 = k {4g..4g+3}, 4-7 = k {16+4g..}.
__device__ __forceinline__ f16x8 pack_frag(float4 lo, float4 hi) {
    f16x8 r;
    r[0] = (_Float16)lo.x; r[1] = (_Float16)lo.y;
    r[2] = (_Float16)lo.z; r[3] = (_Float16)lo.w;
    r[4] = (_Float16)hi.x; r[5] = (_Float16)hi.y;
    r[6] = (_Float16)hi.z; r[7] = (_Float16)hi.w;
    return r;
}

// D-tile regs -> next-step B k-slots; pure per-lane (4x v_cvt_pkrtz).
__device__ __forceinline__ f16x8 pack_state(f32x4 a, f32x4 b) {
    union { f16x8 v; uint32_t u[4]; } r;
    r.u[0] = __builtin_bit_cast(uint32_t, __builtin_amdgcn_cvt_pkrtz(a[0], a[1]));
    r.u[1] = __builtin_bit_cast(uint32_t, __builtin_amdgcn_cvt_pkrtz(a[2], a[3]));
    r.u[2] = __builtin_bit_cast(uint32_t, __builtin_amdgcn_cvt_pkrtz(b[0], b[1]));
    r.u[3] = __builtin_bit_cast(uint32_t, __builtin_amdgcn_cvt_pkrtz(b[2], b[3]));
    return r.v;
}

// x[t] as B-fragment (k=0..3 live on lane-group 0 only).
__device__ __forceinline__ f16x8 bxpack(float4 xn, bool g0) {
    union { f16x8 v; uint32_t u[4]; } bx;
    bx.u[0] = g0 ? __builtin_bit_cast(uint32_t, __builtin_amdgcn_cvt_pkrtz(xn.x, xn.y)) : 0u;
    bx.u[1] = g0 ? __builtin_bit_cast(uint32_t, __builtin_amdgcn_cvt_pkrtz(xn.z, xn.w)) : 0u;
    bx.u[2] = 0u; bx.u[3] = 0u;
    return bx.v;
}

// 4 uniform roles per 16-batch tile; BOTH recurrence chains fully in-register
// (no LDS op on any chain); all ring reads prefetched one phase before use.
//   A: full L0. chain = 2 par MFMA -> tanh8 -> pack. xc via ring from E.
//   B: full L1. chain = 2 par MFMA(W_hh1, Bh1, C=p) -> tanh8 -> pack;
//      p[i] = MFMA(W_ih1, h0[i], b1) computed the phase BEFORE it's needed.
//   E: xc[t] = W_ih0 x_t + b0 (feed-forward; 4-deep x prefetch).
//   D: head + store (reads h1 ring, off everyone's chain).
// Phase p: E->xc[p]; A->h0[p-2]; B->h1[p-4]; D->out[p-5]. One lgkm-only
// barrier per phase. Within a phase every ring slot is written at parity p&1
// and read at parity (p-1)&1 -> no same-phase aliasing; reuse barrier-separated.
// Role XOR on (blockIdx>>3)&1 pairs heavy(A,B)/light(E,D) waves per SIMD across
// the 2 co-resident blocks. Math identical to R8 -> absmax exactly 0.00390625.
__global__ __launch_bounds__(256, 2) void rnn2_roles(
    const float* __restrict__ X,
    const float* __restrict__ W_ih0, const float* __restrict__ W_hh0,
    const float* __restrict__ b_ih0, const float* __restrict__ b_hh0,
    const float* __restrict__ W_ih1, const float* __restrict__ W_hh1,
    const float* __restrict__ b_ih1, const float* __restrict__ b_hh1,
    const float* __restrict__ W_ll, const float* __restrict__ b_ll,
    float* __restrict__ out)
{
    const int  tid = threadIdx.x;
    const int  wid = tid >> 6;
    const int  l   = tid & 63;
    const int  c   = l & 15;         // batch col within tile / A row m
    const int  g   = l >> 4;         // k-group
    const bool g0  = (g == 0);
    const int  b   = blockIdx.x * 16 + c;
    const int  k0  = 4 * g;
    // 0=A(L0) 1=B(L1) 2=E(xc) 3=D(head); swap A<->E, B<->D on alternate blocks
    const int  role = wid ^ (((blockIdx.x >> 3) & 1) << 1);

    __shared__ f32x4 xcring[2][2][64];  // xc (fp32, exact) [parity][frag][lane]
    __shared__ uint4 h0ring[2][64];     // h0 B-fragments [parity][lane]
    __shared__ uint4 h1ring[2][64];     // h1 B-fragments [parity][lane]

    const float4 z4 = make_float4(0.f, 0.f, 0.f, 0.f);
    union { f16x8 v; uint32_t u[4]; } zz;
    zz.u[0] = zz.u[1] = zz.u[2] = zz.u[3] = 0u;

    // phases 0..519 (last real work at p=516; 130 x 4 keeps unroll static)
    if (role == 0) {
        // ================= A: layer 0, h0 recurrence in registers ==========
        const float* wp = W_hh0 + c * kH;
        const f16x8 A0 = pack_frag(ld4(wp + k0), ld4(wp + 16 + k0));
        wp = W_hh0 + (c + 16) * kH;
        const f16x8 A1 = pack_frag(ld4(wp + k0), ld4(wp + 16 + k0));
        f16x8 Bh0 = zz.v;
        f32x4 xcR0 = {0.f,0.f,0.f,0.f}, xcR1 = {0.f,0.f,0.f,0.f};

        for (int pb = 0; pb < 130; ++pb) {
#pragma unroll
            for (int u = 0; u < 4; ++u) {
                const int p = pb * 4 + u;
                f32x4 nx0, nx1;
                const bool rd = (p >= 1) & (p <= 512);   // prefetch xc[p-1]
                const bool go = (p >= 2) & (p <= 513);   // compute h0[p-2]
                if (rd) {
                    nx0 = xcring[(p - 1) & 1][0][l];
                    nx1 = xcring[(p - 1) & 1][1][l];
                }
                if (go) {
                    f32x4 a0 = MFMA(A0, Bh0, xcR0);
                    f32x4 a1 = MFMA(A1, Bh0, xcR1);
                    f32x4 t0, t1;
#pragma unroll
                    for (int r = 0; r < 4; ++r) { t0[r] = fast_tanh(a0[r]); t1[r] = fast_tanh(a1[r]); }
                    Bh0 = pack_state(t0, t1);
                    h0ring[p & 1][l] = __builtin_bit_cast(uint4, Bh0);
                }
                if (rd) { xcR0 = nx0; xcR1 = nx1; }
                bar_lds();
            }
        }
    } else if (role == 1) {
        // ================= B: layer 1, h1 recurrence in registers ==========
        const float* wp = W_ih1 + c * kH;
        const f16x8 I0 = pack_frag(ld4(wp + k0), ld4(wp + 16 + k0));
        wp = W_ih1 + (c + 16) * kH;
        const f16x8 I1 = pack_frag(ld4(wp + k0), ld4(wp + 16 + k0));
        wp = W_hh1 + c * kH;
        const f16x8 H0w = pack_frag(ld4(wp + k0), ld4(wp + 16 + k0));
        wp = W_hh1 + (c + 16) * kH;
        const f16x8 H1w = pack_frag(ld4(wp + k0), ld4(wp + 16 + k0));
        f32x4 bias1_0, bias1_1;
#pragma unroll
        for (int r = 0; r < 4; ++r) {
            bias1_0[r] = b_ih1[k0 + r]      + b_hh1[k0 + r];
            bias1_1[r] = b_ih1[16 + k0 + r] + b_hh1[16 + k0 + r];
        }
        f16x8 Bh1 = zz.v;
        f32x4 pB0 = {0.f,0.f,0.f,0.f}, pB1 = {0.f,0.f,0.f,0.f};

        for (int pb = 0; pb < 130; ++pb) {
#pragma unroll
            for (int u = 0; u < 4; ++u) {
                const int p = pb * 4 + u;
                f16x8 H;
                const bool rd = (p >= 3) & (p <= 514);   // read h0[p-3]
                const bool go = (p >= 4) & (p <= 515);   // compute h1[p-4]
                if (rd) H = __builtin_bit_cast(f16x8, h0ring[(p - 3) & 1][l]);
                if (go) {
                    // chain: one parallel MFMA pair (C = p, precomputed) -> tanh -> pack
                    f32x4 q0 = MFMA(H0w, Bh1, pB0);
                    f32x4 q1 = MFMA(H1w, Bh1, pB1);
                    f32x4 t0, t1;
#pragma unroll
                    for (int r = 0; r < 4; ++r) { t0[r] = fast_tanh(q0[r]); t1[r] = fast_tanh(q1[r]); }
                    Bh1 = pack_state(t0, t1);
                    h1ring[p & 1][l] = __builtin_bit_cast(uint4, Bh1);
                }
                if (rd) {   // p for NEXT phase (off-chain)
                    pB0 = MFMA(I0, H, bias1_0);
                    pB1 = MFMA(I1, H, bias1_1);
                }
                bar_lds();
            }
        }
    } else if (role == 2) {
        // ================= E: xc producer =================
        const f16x8 W0 = pack_frag(g0 ? ld4(W_ih0 + c * kI) : z4, z4);
        const f16x8 W1 = pack_frag(g0 ? ld4(W_ih0 + (c + 16) * kI) : z4, z4);
        f32x4 bias0_0, bias0_1;
#pragma unroll
        for (int r = 0; r < 4; ++r) {
            bias0_0[r] = b_ih0[k0 + r]      + b_hh0[k0 + r];
            bias0_1[r] = b_ih0[16 + k0 + r] + b_hh0[16 + k0 + r];
        }
        const float* xp = X + (size_t)b * (kT * kI);
        float4 xbuf[4];
#pragma unroll
        for (int u = 0; u < 4; ++u) xbuf[u] = ld4(xp + u * kI);

        for (int pb = 0; pb < 130; ++pb) {
#pragma unroll
            for (int u = 0; u < 4; ++u) {
                const int p = pb * 4 + u;
                if (p < kT) {
                    f16x8 bx = bxpack(xbuf[u], g0);
                    f32x4 c0 = MFMA(W0, bx, bias0_0);
                    f32x4 c1 = MFMA(W1, bx, bias0_1);
                    xcring[p & 1][0][l] = c0;
                    xcring[p & 1][1][l] = c1;
                    int idx = p + 4; idx = idx < kT ? idx : (kT - 1);
                    xbuf[u] = ld4(xp + idx * kI);    // 4-phase slack
                }
                bar_lds();
            }
        }
    } else {
        // ================= D: head + store =================
        const f16x8 All = (c < kO)
            ? pack_frag(ld4(W_ll + c * kH + k0), ld4(W_ll + c * kH + 16 + k0))
            : pack_frag(z4, z4);
        f32x4 biasll;
#pragma unroll
        for (int r = 0; r < 4; ++r) biasll[r] = g0 ? b_ll[r] : 0.f;
        float* op = out + (size_t)b * (kT * kO);

        for (int pb = 0; pb < 130; ++pb) {
#pragma unroll
            for (int u = 0; u < 4; ++u) {
                const int p = pb * 4 + u;
                const bool go = (p >= 5) & (p <= 516);   // out[p-5]
                if (go) {
                    f16x8 H1 = __builtin_bit_cast(f16x8, h1ring[(p - 1) & 1][l]);
                    f32x4 o = MFMA(All, H1, biasll);
                    if (g0) *(float4*)(op + (size_t)(p - 5) * kO) =
                        make_float4(o[0], o[1], o[2], o[3]);
                }
                bar_lds();
            }
        }
    }
}

extern "C" void kernel_launch(void* const* d_in, const int* in_sizes, int n_in,
                              void* d_out, int out_size, void* d_ws, size_t ws_size,
                              hipStream_t stream) {
    const float* X     = (const float*)d_in[0];
    const float* W_ih0 = (const float*)d_in[1];
    const float* W_hh0 = (const float*)d_in[2];
    const float* b_ih0 = (const float*)d_in[3];
    const float* b_hh0 = (const float*)d_in[4];
    const float* W_ih1 = (const float*)d_in[5];
    const float* W_hh1 = (const float*)d_in[6];
    const float* b_ih1 = (const float*)d_in[7];
    const float* b_hh1 = (const float*)d_in[8];
    const float* W_ll  = (const float*)d_in[9];
    const float* b_ll  = (const float*)d_in[10];
    float* out = (float*)d_out;

    rnn2_roles<<<dim3(kB / 16), dim3(256), 0, stream>>>(
        X, W_ih0, W_hh0, b_ih0, b_hh0, W_ih1, W_hh1, b_ih1, b_hh1, W_ll, b_ll, out);
}

// Round 15
// 140.703 us; speedup vs baseline: 1.0577x; 1.0577x over previous
//
#include <hip/hip_runtime.h>
#include <cstddef>
#include <cstdint>

// B=8192, T=512, I=4, H=32, O=4 — 2-layer tanh RNN + linear head, fp32 I/O.
constexpr int kB = 8192, kT = 512, kI = 4, kH = 32, kO = 4;

typedef _Float16 f16x8 __attribute__((ext_vector_type(8)));
typedef float    f32x4 __attribute__((ext_vector_type(4)));

#define MFMA(a, b, c) __builtin_amdgcn_mfma_f32_16x16x32_f16((a), (b), (c), 0, 0, 0)

// Barrier waiting on LDS ops only (global loads/stores stay in flight).
__device__ __forceinline__ void bar_lds() {
    asm volatile("s_waitcnt lgkmcnt(0)" ::: "memory");
    __builtin_amdgcn_s_barrier();
    __builtin_amdgcn_sched_barrier(0);
}

// Vector rational tanh, Pade[5/4]:
//   tanh x ~= x*(945 + 105u + u^2) / (945 + 420u + 15u^2),  u=x^2, clamp ±3.5.
// All-FMA except ONE v_rcp per element; elementwise on f32x4 so the compiler
// emits packed v_pk_*_f32 (full-rate, 4-cy dep) — dependency chain ~110 cy vs
// ~220-260 for exp2+rcp tanh (two serial quarter-rate trans ops @ ~80 cy).
// Numerics: R12 ran this exact formula -> absmax identical to fast_tanh.
__device__ __forceinline__ f32x4 rtanh4(f32x4 x) {
    const f32x4 vhi = { 3.5f,  3.5f,  3.5f,  3.5f};
    const f32x4 vlo = {-3.5f, -3.5f, -3.5f, -3.5f};
    const f32x4 c945 = {945.f, 945.f, 945.f, 945.f};
    const f32x4 c420 = {420.f, 420.f, 420.f, 420.f};
    const f32x4 c105 = {105.f, 105.f, 105.f, 105.f};
    const f32x4 c15  = { 15.f,  15.f,  15.f,  15.f};
    f32x4 xc = __builtin_elementwise_min(__builtin_elementwise_max(x, vlo), vhi);
    f32x4 u  = xc * xc;
    f32x4 n  = __builtin_elementwise_fma(u, u + c105, c945);
    f32x4 d  = __builtin_elementwise_fma(u, __builtin_elementwise_fma(u, c15, c420), c945);
    f32x4 xn = xc * n;
    f32x4 r;
    r[0] = __builtin_amdgcn_rcpf(d[0]);
    r[1] = __builtin_amdgcn_rcpf(d[1]);
    r[2] = __builtin_amdgcn_rcpf(d[2]);
    r[3] = __builtin_amdgcn_rcpf(d[3]);
    return xn * r;
}

__device__ __forceinline__ float4 ld4(const float* p) { return *(const float4*)p; }

// A/B fragment from two float4s: elems 0-3 = k {4g..4g+3}, 4-7 = k {16+4g..}.
__device__ __forceinline__ f16x8 pack_frag(float4 lo, float4 hi) {
    f16x8 r;
    r[0] = (_Float16)lo.x; r[1] = (_Float16)lo.y;
    r[2] = (_Float16)lo.z; r[3] = (_Float16)lo.w;
    r[4] = (_Float16)hi.x; r[5] = (_Float16)hi.y;
    r[6] = (_Float16)hi.z; r[7] = (_Float16)hi.w;
    return r;
}

// Assemble a B-operand fragment from two uint2 halves (k 0-15 | k 16-31).
__device__ __forceinline__ f16x8 asm_frag(uint2 lo, uint2 hi) {
    union { f16x8 v; uint2 p[2]; } r;
    r.p[0] = lo; r.p[1] = hi;
    return r.v;
}

// One D-half-tile (4 fp32 rows) -> 8B of B k-slots (2x v_cvt_pkrtz).
__device__ __forceinline__ uint2 pack_half(f32x4 t) {
    uint2 r;
    r.x = __builtin_bit_cast(uint32_t, __builtin_amdgcn_cvt_pkrtz(t[0], t[1]));
    r.y = __builtin_bit_cast(uint32_t, __builtin_amdgcn_cvt_pkrtz(t[2], t[3]));
    return r;
}

// x[t] as B-fragment. No lane select needed: g!=0 lanes' k-slots (k>=4) and
// slots u[2],u[3] (k>=16) multiply AGAINST ZEROED A-columns of the padded
// W_ih0 operand; x is finite so junk*0 == 0. Saves 2 cndmask per call.
__device__ __forceinline__ f16x8 bxpack(float4 xn) {
    union { f16x8 v; uint32_t u[4]; } bx;
    bx.u[0] = __builtin_bit_cast(uint32_t, __builtin_amdgcn_cvt_pkrtz(xn.x, xn.y));
    bx.u[1] = __builtin_bit_cast(uint32_t, __builtin_amdgcn_cvt_pkrtz(xn.z, xn.w));
    bx.u[2] = 0u; bx.u[3] = 0u;
    return bx.v;
}

// R8 structure (best measured: 124us, 637 cy/step) with the tanh chain cut:
//  (1) rtanh4: packed-FMA rational tanh, chain ~110 cy vs ~220-260 (the fitted
//      dominant serial term across R5/R8/R12/R14).
//  (2) bxpack without lane selects.
//  (3) B-wave p/q MFMAs de-chained (q starts at barrier from registers),
//      combined by one packed add before tanh (R12-proven absmax-identical).
// Roles: wave0/1 = h0 rows 0-15/16-31; wave2/3 = h1 rows 0-15/16-31 (+head).
// Pipeline index i: A computes h0[i]; B computes h1[i-1]; head emits i-2.
__global__ __launch_bounds__(256, 2) void rnn2_quad4(
    const float* __restrict__ X,
    const float* __restrict__ W_ih0, const float* __restrict__ W_hh0,
    const float* __restrict__ b_ih0, const float* __restrict__ b_hh0,
    const float* __restrict__ W_ih1, const float* __restrict__ W_hh1,
    const float* __restrict__ b_ih1, const float* __restrict__ b_hh1,
    const float* __restrict__ W_ll, const float* __restrict__ b_ll,
    float* __restrict__ out)
{
    const int  tid  = threadIdx.x;
    const int  wid  = tid >> 6;        // 0,1 = L0 halves; 2,3 = L1 halves
    const int  half = wid & 1;         // 0: rows 0-15, 1: rows 16-31
    const int  isB  = wid >> 1;
    const int  l    = tid & 63;
    const int  c    = l & 15;          // batch col within tile
    const int  g    = l >> 4;          // k-group
    const bool g0   = (g == 0);
    const int  b    = blockIdx.x * 16 + c;
    const int  k0   = 4 * g;
    const int  ro   = half * 16;       // row offset of this wave's half

    __shared__ uint2 h0buf[2][2][64];  // [step parity][half][lane]
    __shared__ uint2 h1buf[2][2][64];

    // zero-init both parities (h0[-1]=h1[-1]=h1[-2]=0 fall out of this)
    h0buf[tid >> 7][(tid >> 6) & 1][tid & 63] = make_uint2(0u, 0u);
    h1buf[tid >> 7][(tid >> 6) & 1][tid & 63] = make_uint2(0u, 0u);
    __syncthreads();

    const float4 z4 = make_float4(0.f, 0.f, 0.f, 0.f);
    const f32x4  zf = {0.f, 0.f, 0.f, 0.f};

    if (isB == 0) {
        // ======== A-wave: layer 0, rows ro..ro+15 ========
        const float* wp = W_hh0 + (c + ro) * kH;
        const f16x8 Ahh = pack_frag(ld4(wp + k0), ld4(wp + 16 + k0));
        const f16x8 Aih = pack_frag(g0 ? ld4(W_ih0 + (c + ro) * kI) : z4, z4);
        f32x4 bias0;
#pragma unroll
        for (int r = 0; r < 4; ++r) bias0[r] = b_ih0[ro + k0 + r] + b_hh0[ro + k0 + r];

        uint2 myh = make_uint2(0u, 0u);   // own half of h0[i-1] (k-slots)
        f32x4 xc;                          // xc[i] = W_ih0·x[i] + b0 (this half)
        const float* xp = X + (size_t)b * (kT * kI);

        float4 xv0 = ld4(xp);
        float4 xv1 = ld4(xp + 1 * kI);
        float4 xv2 = ld4(xp + 2 * kI);
        float4 xcur[4];
#pragma unroll
        for (int u = 0; u < 4; ++u) xcur[u] = ld4(xp + (3 + u) * kI);
        xc = MFMA(Aih, bxpack(xv0), bias0);

        auto stepA = [&](float4 xn, int i) {
            const int rp = (i - 1) & 1, wpar = i & 1;
            uint2 sib = h0buf[rp][half ^ 1][l];          // sibling half (ds_read)
            f32x4 xcn = MFMA(Aih, bxpack(xn), bias0);    // independent; covers read
            f16x8 Bh0 = half == 0 ? asm_frag(myh, sib) : asm_frag(sib, myh);
            f32x4 a = MFMA(Ahh, Bh0, xc);
            myh = pack_half(rtanh4(a));
            h0buf[wpar][half][l] = myh;
            xc = xcn;
        };

        stepA(xv1, 0); bar_lds();   // i = 0
        stepA(xv2, 1); bar_lds();   // i = 1
        for (int tb = 0; tb < 128; ++tb) {
            const int i0 = 2 + tb * 4;
            float4 xnxt[4];
#pragma unroll
            for (int u = 0; u < 4; ++u) {
                int idx = i0 + 5 + u;
                idx = idx < kT ? idx : (kT - 1);
                xnxt[u] = ld4(xp + idx * kI);
            }
#pragma unroll
            for (int u = 0; u < 4; ++u) { stepA(xcur[u], i0 + u); bar_lds(); }
#pragma unroll
            for (int u = 0; u < 4; ++u) xcur[u] = xnxt[u];
        }
    } else {
        // ======== B-wave: layer 1 rows ro..ro+15 (+ head on half 0) ========
        const float* wp = W_ih1 + (c + ro) * kH;
        const f16x8 Aih1 = pack_frag(ld4(wp + k0), ld4(wp + 16 + k0));
        wp = W_hh1 + (c + ro) * kH;
        const f16x8 Ahh1 = pack_frag(ld4(wp + k0), ld4(wp + 16 + k0));
        const f16x8 All = (half == 0 && c < kO)
            ? pack_frag(ld4(W_ll + c * kH + k0), ld4(W_ll + c * kH + 16 + k0))
            : pack_frag(z4, z4);

        f32x4 bias1, biasll;
#pragma unroll
        for (int r = 0; r < 4; ++r) {
            bias1[r]  = b_ih1[ro + k0 + r] + b_hh1[ro + k0 + r];
            biasll[r] = g0 ? b_ll[r] : 0.f;
        }

        uint2 myh1 = make_uint2(0u, 0u);  // own half of h1[i-2]
        float* op = out + (size_t)b * (kT * kO);

        auto stepB = [&](int i, bool store) {
            const int rp = (i - 1) & 1, wpar = i & 1;
            uint2 h0lo = h0buf[rp][0][l];
            uint2 h0hi = h0buf[rp][1][l];
            uint2 sib1 = h1buf[rp][half ^ 1][l];
            f16x8 Bh1v = half == 0 ? asm_frag(myh1, sib1) : asm_frag(sib1, myh1);
            f32x4 o;
            if (half == 0) o = MFMA(All, Bh1v, biasll);   // head, step i-2 (off-chain)
            // q from registers (issues at barrier exit); p after the h0 reads;
            // combined by one packed add — no MFMA->MFMA chain.
            f32x4 q = MFMA(Ahh1, Bh1v, bias1);
            f32x4 p = MFMA(Aih1, asm_frag(h0lo, h0hi), zf);
            myh1 = pack_half(rtanh4(p + q));
            h1buf[wpar][half][l] = myh1;
            if (store && half == 0 && g0)
                *(float4*)(op + (size_t)(i - 2) * kO) = make_float4(o[0], o[1], o[2], o[3]);
        };

        bar_lds();                    // i = 0: buffers already zero; just sync
        stepB(1, false); bar_lds();   // i = 1: h1[0] from h0[0], h1[-1]=0
        for (int tb = 0; tb < 128; ++tb) {
            const int i0 = 2 + tb * 4;
#pragma unroll
            for (int u = 0; u < 4; ++u) { stepB(i0 + u, true); bar_lds(); }
        }
    }
}

extern "C" void kernel_launch(void* const* d_in, const int* in_sizes, int n_in,
                              void* d_out, int out_size, void* d_ws, size_t ws_size,
                              hipStream_t stream) {
    const float* X     = (const float*)d_in[0];
    const float* W_ih0 = (const float*)d_in[1];
    const float* W_hh0 = (const float*)d_in[2];
    const float* b_ih0 = (const float*)d_in[3];
    const float* b_hh0 = (const float*)d_in[4];
    const float* W_ih1 = (const float*)d_in[5];
    const float* W_hh1 = (const float*)d_in[6];
    const float* b_ih1 = (const float*)d_in[7];
    const float* b_hh1 = (const float*)d_in[8];
    const float* W_ll  = (const float*)d_in[9];
    const float* b_ll  = (const float*)d_in[10];
    float* out = (float*)d_out;

    rnn2_quad4<<<dim3(kB / 16), dim3(256), 0, stream>>>(
        X, W_ih0, W_hh0, b_ih0, b_hh0, W_ih1, W_hh1, b_ih1, b_hh1, W_ll, b_ll, out);
}

// Round 16
// 122.295 us; speedup vs baseline: 1.2169x; 1.1505x over previous
//
#include <hip/hip_runtime.h>
#include <cstddef>
#include <cstdint>

// B=8192, T=512, I=4, H=32, O=4 — 2-layer tanh RNN + linear head, fp32 I/O.
constexpr int kB = 8192, kT = 512, kI = 4, kH = 32, kO = 4;

typedef _Float16 f16x8 __attribute__((ext_vector_type(8)));
typedef float    f32x4 __attribute__((ext_vector_type(4)));

#define MFMA(a, b, c) __builtin_amdgcn_mfma_f32_16x16x32_f16((a), (b), (c), 0, 0, 0)

// K = 2*log2(e): pre-scaling W_hh/W_ih/bias by K makes the MFMA output directly
// usable by exp2 — removes the x*K multiply from the serial tanh chain.
constexpr float kPre = 2.8853900817779268f;

// Barrier waiting on LDS ops only (global loads/stores stay in flight).
__device__ __forceinline__ void bar_lds() {
    asm volatile("s_waitcnt lgkmcnt(0)" ::: "memory");
    __builtin_amdgcn_s_barrier();
    __builtin_amdgcn_sched_barrier(0);
}

// tanh for PRE-SCALED input: x' = K*x already. tanh = 1 - 2/(exp2(x')+1).
// Chain: exp2 -> add -> rcp -> fma. Saturates correctly at +/-inf.
__device__ __forceinline__ float fast_tanh_pre(float xp) {
    float e = __builtin_amdgcn_exp2f(xp);
    return fmaf(-2.0f, __builtin_amdgcn_rcpf(e + 1.0f), 1.0f);
}

__device__ __forceinline__ float4 ld4(const float* p) { return *(const float4*)p; }

__device__ __forceinline__ float4 scl4(float4 v, float s) {
    return make_float4(v.x * s, v.y * s, v.z * s, v.w * s);
}

// A/B fragment from two float4s: elems 0-3 = k {4g..4g+3}, 4-7 = k {16+4g..}.
__device__ __forceinline__ f16x8 pack_frag(float4 lo, float4 hi) {
    f16x8 r;
    r[0] = (_Float16)lo.x; r[1] = (_Float16)lo.y;
    r[2] = (_Float16)lo.z; r[3] = (_Float16)lo.w;
    r[4] = (_Float16)hi.x; r[5] = (_Float16)hi.y;
    r[6] = (_Float16)hi.z; r[7] = (_Float16)hi.w;
    return r;
}

// Assemble a B-operand fragment from two uint2 halves (k 0-15 | k 16-31).
__device__ __forceinline__ f16x8 asm_frag(uint2 lo, uint2 hi) {
    union { f16x8 v; uint2 p[2]; } r;
    r.p[0] = lo; r.p[1] = hi;
    return r.v;
}

// One D-half-tile (4 fp32 rows) -> 8B of B k-slots (2x v_cvt_pkrtz).
__device__ __forceinline__ uint2 pack_half(f32x4 t) {
    uint2 r;
    r.x = __builtin_bit_cast(uint32_t, __builtin_amdgcn_cvt_pkrtz(t[0], t[1]));
    r.y = __builtin_bit_cast(uint32_t, __builtin_amdgcn_cvt_pkrtz(t[2], t[3]));
    return r;
}

// x[t] as B-fragment. No lane masking: junk k-slots multiply against ZEROED
// A-columns of the padded W_ih0 operand (finite x -> junk*0 == 0).
__device__ __forceinline__ f16x8 bxpack(float4 xn) {
    union { f16x8 v; uint32_t u[4]; } bx;
    bx.u[0] = __builtin_bit_cast(uint32_t, __builtin_amdgcn_cvt_pkrtz(xn.x, xn.y));
    bx.u[1] = __builtin_bit_cast(uint32_t, __builtin_amdgcn_cvt_pkrtz(xn.z, xn.w));
    bx.u[2] = 0u; bx.u[3] = 0u;
    return bx.v;
}

// R8 structure verbatim (proven best: 124us): 4-wave role split per 16-batch
// tile, per-step lgkm-only barrier, double-buffered half exchanges.
// Only changes vs R8: (1) W_hh/W_ih/biases pre-scaled by K=2log2e so the tanh
// chain loses its multiply; (2) tanh tail is a single fma; (3) bxpack unmasked.
// All are chain/issue cuts with zero structural or numerical consequence.
//   wave0 (A0): h0 rows 0-15    wave1 (A1): h0 rows 16-31
//   wave2 (B0): h1 rows 0-15 + head   wave3 (B1): h1 rows 16-31
// Pipeline index i: A computes h0[i]; B computes h1[i-1]; head emits i-2.
__global__ __launch_bounds__(256, 2) void rnn2_quad5(
    const float* __restrict__ X,
    const float* __restrict__ W_ih0, const float* __restrict__ W_hh0,
    const float* __restrict__ b_ih0, const float* __restrict__ b_hh0,
    const float* __restrict__ W_ih1, const float* __restrict__ W_hh1,
    const float* __restrict__ b_ih1, const float* __restrict__ b_hh1,
    const float* __restrict__ W_ll, const float* __restrict__ b_ll,
    float* __restrict__ out)
{
    const int  tid  = threadIdx.x;
    const int  wid  = tid >> 6;        // 0,1 = L0 halves; 2,3 = L1 halves
    const int  half = wid & 1;         // 0: rows 0-15, 1: rows 16-31
    const int  isB  = wid >> 1;
    const int  l    = tid & 63;
    const int  c    = l & 15;          // batch col within tile
    const int  g    = l >> 4;          // k-group
    const bool g0   = (g == 0);
    const int  b    = blockIdx.x * 16 + c;
    const int  k0   = 4 * g;
    const int  ro   = half * 16;       // row offset of this wave's half

    __shared__ uint2 h0buf[2][2][64];  // [step parity][half][lane]
    __shared__ uint2 h1buf[2][2][64];

    // zero-init both parities (h0[-1]=h1[-1]=h1[-2]=0 fall out of this)
    h0buf[tid >> 7][(tid >> 6) & 1][tid & 63] = make_uint2(0u, 0u);
    h1buf[tid >> 7][(tid >> 6) & 1][tid & 63] = make_uint2(0u, 0u);
    __syncthreads();

    const float4 z4 = make_float4(0.f, 0.f, 0.f, 0.f);

    if (isB == 0) {
        // ======== A-wave: layer 0, rows ro..ro+15 (weights pre-scaled) ========
        const float* wp = W_hh0 + (c + ro) * kH;
        const f16x8 Ahh = pack_frag(scl4(ld4(wp + k0), kPre),
                                    scl4(ld4(wp + 16 + k0), kPre));
        const f16x8 Aih = pack_frag(g0 ? scl4(ld4(W_ih0 + (c + ro) * kI), kPre) : z4, z4);
        f32x4 bias0;
#pragma unroll
        for (int r = 0; r < 4; ++r)
            bias0[r] = (b_ih0[ro + k0 + r] + b_hh0[ro + k0 + r]) * kPre;

        uint2 myh = make_uint2(0u, 0u);   // own half of h0[i-1] (k-slots)
        f32x4 xc;                          // xc[i] = K*(W_ih0·x[i] + b0), this half
        const float* xp = X + (size_t)b * (kT * kI);

        float4 xv0 = ld4(xp);
        float4 xv1 = ld4(xp + 1 * kI);
        float4 xv2 = ld4(xp + 2 * kI);
        float4 xcur[4];
#pragma unroll
        for (int u = 0; u < 4; ++u) xcur[u] = ld4(xp + (3 + u) * kI);
        xc = MFMA(Aih, bxpack(xv0), bias0);

        auto stepA = [&](float4 xn, int i) {
            const int rp = (i - 1) & 1, wpar = i & 1;
            uint2 sib = h0buf[rp][half ^ 1][l];          // sibling half (ds_read)
            f32x4 xcn = MFMA(Aih, bxpack(xn), bias0);    // independent; covers read
            f16x8 Bh0 = half == 0 ? asm_frag(myh, sib) : asm_frag(sib, myh);
            f32x4 a = MFMA(Ahh, Bh0, xc);                // a is already K-scaled
            f32x4 t;
#pragma unroll
            for (int r = 0; r < 4; ++r) t[r] = fast_tanh_pre(a[r]);
            myh = pack_half(t);
            h0buf[wpar][half][l] = myh;
            xc = xcn;
        };

        stepA(xv1, 0); bar_lds();   // i = 0
        stepA(xv2, 1); bar_lds();   // i = 1
        for (int tb = 0; tb < 128; ++tb) {
            const int i0 = 2 + tb * 4;
            float4 xnxt[4];
#pragma unroll
            for (int u = 0; u < 4; ++u) {
                int idx = i0 + 5 + u;
                idx = idx < kT ? idx : (kT - 1);
                xnxt[u] = ld4(xp + idx * kI);
            }
#pragma unroll
            for (int u = 0; u < 4; ++u) { stepA(xcur[u], i0 + u); bar_lds(); }
#pragma unroll
            for (int u = 0; u < 4; ++u) xcur[u] = xnxt[u];
        }
    } else {
        // ======== B-wave: layer 1 rows ro..ro+15 (+ head on half 0) ========
        const float* wp = W_ih1 + (c + ro) * kH;
        const f16x8 Aih1 = pack_frag(scl4(ld4(wp + k0), kPre),
                                     scl4(ld4(wp + 16 + k0), kPre));
        wp = W_hh1 + (c + ro) * kH;
        const f16x8 Ahh1 = pack_frag(scl4(ld4(wp + k0), kPre),
                                     scl4(ld4(wp + 16 + k0), kPre));
        const f16x8 All = (half == 0 && c < kO)
            ? pack_frag(ld4(W_ll + c * kH + k0), ld4(W_ll + c * kH + 16 + k0))
            : pack_frag(z4, z4);           // head stays UNscaled

        f32x4 bias1, biasll;
#pragma unroll
        for (int r = 0; r < 4; ++r) {
            bias1[r]  = (b_ih1[ro + k0 + r] + b_hh1[ro + k0 + r]) * kPre;
            biasll[r] = g0 ? b_ll[r] : 0.f;
        }

        uint2 myh1 = make_uint2(0u, 0u);  // own half of h1[i-2]
        float* op = out + (size_t)b * (kT * kO);

        auto stepB = [&](int i, bool store) {
            const int rp = (i - 1) & 1, wpar = i & 1;
            uint2 h0lo = h0buf[rp][0][l];
            uint2 h0hi = h0buf[rp][1][l];
            uint2 sib1 = h1buf[rp][half ^ 1][l];
            f16x8 Bh0  = asm_frag(h0lo, h0hi);
            f16x8 Bh1v = half == 0 ? asm_frag(myh1, sib1) : asm_frag(sib1, myh1);
            f32x4 o;
            if (half == 0) o = MFMA(All, Bh1v, biasll);   // head, step i-2
            f32x4 cc = MFMA(Aih1, Bh0, bias1);            // K-scaled
            cc = MFMA(Ahh1, Bh1v, cc);
            f32x4 t;
#pragma unroll
            for (int r = 0; r < 4; ++r) t[r] = fast_tanh_pre(cc[r]);
            myh1 = pack_half(t);
            h1buf[wpar][half][l] = myh1;
            if (store && half == 0 && g0)
                *(float4*)(op + (size_t)(i - 2) * kO) = make_float4(o[0], o[1], o[2], o[3]);
        };

        bar_lds();                    // i = 0: buffers already zero; just sync
        stepB(1, false); bar_lds();   // i = 1: h1[0] from h0[0], h1[-1]=0
        for (int tb = 0; tb < 128; ++tb) {
            const int i0 = 2 + tb * 4;
#pragma unroll
            for (int u = 0; u < 4; ++u) { stepB(i0 + u, true); bar_lds(); }
        }
    }
}

extern "C" void kernel_launch(void* const* d_in, const int* in_sizes, int n_in,
                              void* d_out, int out_size, void* d_ws, size_t ws_size,
                              hipStream_t stream) {
    const float* X     = (const float*)d_in[0];
    const float* W_ih0 = (const float*)d_in[1];
    const float* W_hh0 = (const float*)d_in[2];
    const float* b_ih0 = (const float*)d_in[3];
    const float* b_hh0 = (const float*)d_in[4];
    const float* W_ih1 = (const float*)d_in[5];
    const float* W_hh1 = (const float*)d_in[6];
    const float* b_ih1 = (const float*)d_in[7];
    const float* b_hh1 = (const float*)d_in[8];
    const float* W_ll  = (const float*)d_in[9];
    const float* b_ll  = (const float*)d_in[10];
    float* out = (float*)d_out;

    rnn2_quad5<<<dim3(kB / 16), dim3(256), 0, stream>>>(
        X, W_ih0, W_hh0, b_ih0, b_hh0, W_ih1, W_hh1, b_ih1, b_hh1, W_ll, b_ll, out);
}